// Round 5
// baseline (49.583 us; speedup 1.0000x reference)
//
#include <hip/hip_runtime.h>
#include <math.h>
#include <stdint.h>

// Problem constants (match reference)
#define BB 65536
#define KK 10
#define EE 128
#define VV 100000

constexpr int BLOCK = 256;
constexpr int BPB   = 32;            // 32 groups of 8 lanes per block
constexpr int GRID  = BB / BPB;      // 2048 blocks (fp8 path)

constexpr size_t TBL_OFF   = 32768;              // fp8 table offset in ws
constexpr size_t TBL_BYTES = (size_t)VV * EE;    // 12.8 MB fp8

__device__ __forceinline__ float softplus_f(float x) {
    float ax = fabsf(x);
    return fmaxf(x, 0.0f) + __logf(1.0f + __expf(-ax));
}

// ---- fp32 -> fp8 e4m3 (RNE, HW cvt) table conversion; also zeroes out[0] --
__global__ __launch_bounds__(256) void
convert_fp8_kernel(const float* __restrict__ emb, uint4* __restrict__ tbl,
                   float* __restrict__ out) {
    if (blockIdx.x == 0 && threadIdx.x == 0) out[0] = 0.0f;  // ordered before loss kernel
    const int nq = VV * EE / 16;                 // 800K chunks of 16 elems
    const int stride = gridDim.x * blockDim.x;
    for (int q = blockIdx.x * blockDim.x + threadIdx.x; q < nq; q += stride) {
        const float4* src = (const float4*)emb + (size_t)q * 4;
        const float4 f0 = src[0], f1 = src[1], f2 = src[2], f3 = src[3];
        uint32_t w[4];
        int v;
        v = 0;
        v = __builtin_amdgcn_cvt_pk_fp8_f32(f0.x, f0.y, v, false);
        v = __builtin_amdgcn_cvt_pk_fp8_f32(f0.z, f0.w, v, true);
        w[0] = (uint32_t)v;
        v = 0;
        v = __builtin_amdgcn_cvt_pk_fp8_f32(f1.x, f1.y, v, false);
        v = __builtin_amdgcn_cvt_pk_fp8_f32(f1.z, f1.w, v, true);
        w[1] = (uint32_t)v;
        v = 0;
        v = __builtin_amdgcn_cvt_pk_fp8_f32(f2.x, f2.y, v, false);
        v = __builtin_amdgcn_cvt_pk_fp8_f32(f2.z, f2.w, v, true);
        w[2] = (uint32_t)v;
        v = 0;
        v = __builtin_amdgcn_cvt_pk_fp8_f32(f3.x, f3.y, v, false);
        v = __builtin_amdgcn_cvt_pk_fp8_f32(f3.z, f3.w, v, true);
        w[3] = (uint32_t)v;
        tbl[q] = make_uint4(w[0], w[1], w[2], w[3]);
    }
}

// ---- fp8 gather + loss ---------------------------------------------------
__device__ __forceinline__ void decode16(const uint4& u, float* f) {
    const uint32_t a[4] = {u.x, u.y, u.z, u.w};
    #pragma unroll
    for (int i = 0; i < 4; ++i) {
        auto lo = __builtin_amdgcn_cvt_pk_f32_fp8((int)a[i], false);
        auto hi = __builtin_amdgcn_cvt_pk_f32_fp8((int)a[i], true);
        f[4 * i + 0] = lo[0];
        f[4 * i + 1] = lo[1];
        f[4 * i + 2] = hi[0];
        f[4 * i + 3] = hi[1];
    }
}

__device__ __forceinline__ float dotd16(const float* cf, const uint4& u) {
    const uint32_t a[4] = {u.x, u.y, u.z, u.w};
    float s = 0.0f;
    #pragma unroll
    for (int i = 0; i < 4; ++i) {
        auto lo = __builtin_amdgcn_cvt_pk_f32_fp8((int)a[i], false);
        auto hi = __builtin_amdgcn_cvt_pk_f32_fp8((int)a[i], true);
        s = fmaf(cf[4 * i + 0], lo[0], s);
        s = fmaf(cf[4 * i + 1], lo[1], s);
        s = fmaf(cf[4 * i + 2], hi[0], s);
        s = fmaf(cf[4 * i + 3], hi[1], s);
    }
    return s;
}

__global__ __launch_bounds__(BLOCK, 4) void
w2v_loss_fp8_kernel(const int* __restrict__ cw,
                    const int* __restrict__ ow,
                    const int* __restrict__ neg,
                    const uint4* __restrict__ rows,   // one row = 8 uint4 (128 B)
                    float* __restrict__ out) {
    const int tid = threadIdx.x;
    const int li  = tid & 7;               // lane-in-group (8-lane groups)
    const int grp = tid >> 3;              // 0..31
    const int b0  = blockIdx.x * BPB;

    // ---- stage this block's 384 indices through LDS (coalesced) ----
    __shared__ int s_cw[BPB];
    __shared__ int s_ow[BPB];
    __shared__ int s_neg[BPB * KK];
    if (tid < BPB)              s_cw[tid]       = cw[b0 + tid];
    else if (tid < 2 * BPB)     s_ow[tid - BPB] = ow[b0 + tid - BPB];
    for (int i = tid; i < BPB * KK; i += BLOCK) s_neg[i] = neg[b0 * KK + i];
    __syncthreads();

    // ---- issue ALL 12 row gathers before any compute (max MLP) ----
    const int c = s_cw[grp];
    const int o = s_ow[grp];
    const uint4 ec = rows[(size_t)c * 8 + li];
    const uint4 eo = rows[(size_t)o * 8 + li];
    uint4 en[KK];
    #pragma unroll
    for (int k = 0; k < KK; ++k)
        en[k] = rows[(size_t)s_neg[grp * KK + k] * 8 + li];

    // ---- compute ----
    float cf[16];
    decode16(ec, cf);
    float pd = dotd16(cf, eo);
    float nd[KK];
    #pragma unroll
    for (int k = 0; k < KK; ++k) nd[k] = dotd16(cf, en[k]);

    // Reduce across the 8-lane group: masks 1,2,4.
    #pragma unroll
    for (int s = 1; s < 8; s <<= 1) {
        pd += __shfl_xor(pd, s);
        #pragma unroll
        for (int k = 0; k < KK; ++k) nd[k] += __shfl_xor(nd[k], s);
    }

    float loss = softplus_f(-pd);
    #pragma unroll
    for (int k = 0; k < KK; ++k) loss += softplus_f(nd[k]);

    __shared__ float smem[BPB];
    if (li == 0) smem[grp] = loss;
    __syncthreads();
    if (tid == 0) {
        float s = 0.0f;
        #pragma unroll
        for (int g = 0; g < BPB; ++g) s += smem[g];
        atomicAdd(out, s * (1.0f / (float)BB));   // pre-scaled; one atomic per block
    }
}

// ---- fp32 fallback (ws too small; round-2 structure) --------------------
__device__ __forceinline__ float dot8(const float4& a0, const float4& a1,
                                      const float4& b0, const float4& b1) {
    float s = a0.x * b0.x;
    s = fmaf(a0.y, b0.y, s); s = fmaf(a0.z, b0.z, s); s = fmaf(a0.w, b0.w, s);
    s = fmaf(a1.x, b1.x, s); s = fmaf(a1.y, b1.y, s);
    s = fmaf(a1.z, b1.z, s); s = fmaf(a1.w, b1.w, s);
    return s;
}

__global__ __launch_bounds__(BLOCK) void
w2v_loss_f32_kernel(const int* __restrict__ cw,
                    const int* __restrict__ ow,
                    const int* __restrict__ neg,
                    const float* __restrict__ emb,
                    float* __restrict__ partial) {
    const int tid = threadIdx.x;
    const int li  = tid & 15;
    const int grp = tid >> 4;
    const int b   = blockIdx.x * 16 + grp;

    const int c = cw[b];
    const int o = ow[b];
    const float4* ebase = (const float4*)emb;
    const size_t f4 = (size_t)li * 2;

    const float4 ec0 = ebase[(size_t)c * 32 + f4];
    const float4 ec1 = ebase[(size_t)c * 32 + f4 + 1];
    const float4 eo0 = ebase[(size_t)o * 32 + f4];
    const float4 eo1 = ebase[(size_t)o * 32 + f4 + 1];

    float pd = dot8(ec0, ec1, eo0, eo1);
    float nd[KK];
    #pragma unroll
    for (int k = 0; k < KK; ++k) {
        const int n = neg[b * KK + k];
        const float4 en0 = ebase[(size_t)n * 32 + f4];
        const float4 en1 = ebase[(size_t)n * 32 + f4 + 1];
        nd[k] = dot8(ec0, ec1, en0, en1);
    }
    #pragma unroll
    for (int s = 1; s < 16; s <<= 1) {
        pd += __shfl_xor(pd, s);
        #pragma unroll
        for (int k = 0; k < KK; ++k) nd[k] += __shfl_xor(nd[k], s);
    }
    float loss = softplus_f(-pd);
    #pragma unroll
    for (int k = 0; k < KK; ++k) loss += softplus_f(nd[k]);

    __shared__ float smem[16];
    if (li == 0) smem[grp] = loss;
    __syncthreads();
    if (tid == 0) {
        float s = 0.0f;
        #pragma unroll
        for (int g = 0; g < 16; ++g) s += smem[g];
        partial[blockIdx.x] = s;
    }
}

__global__ __launch_bounds__(256) void
w2v_reduce_kernel(const float* __restrict__ partial, int n, float* __restrict__ out) {
    __shared__ float smem[256];
    float s = 0.0f;
    for (int i = threadIdx.x; i < n; i += 256) s += partial[i];
    smem[threadIdx.x] = s;
    __syncthreads();
    for (int step = 128; step > 0; step >>= 1) {
        if (threadIdx.x < step) smem[threadIdx.x] += smem[threadIdx.x + step];
        __syncthreads();
    }
    if (threadIdx.x == 0) out[0] = smem[0] / (float)BB;
}

extern "C" void kernel_launch(void* const* d_in, const int* in_sizes, int n_in,
                              void* d_out, int out_size, void* d_ws, size_t ws_size,
                              hipStream_t stream) {
    const int*   cw  = (const int*)d_in[0];
    const int*   ow  = (const int*)d_in[1];
    const int*   neg = (const int*)d_in[2];
    const float* emb = (const float*)d_in[3];
    float* out = (float*)d_out;

    if (ws_size >= TBL_OFF + TBL_BYTES) {
        uint4* tbl = (uint4*)((char*)d_ws + TBL_OFF);
        convert_fp8_kernel<<<2048, 256, 0, stream>>>(emb, tbl, out);
        w2v_loss_fp8_kernel<<<GRID, BLOCK, 0, stream>>>(cw, ow, neg, tbl, out);
    } else {
        float* partial = (float*)d_ws;
        w2v_loss_f32_kernel<<<BB / 16, BLOCK, 0, stream>>>(cw, ow, neg, emb, partial);
        w2v_reduce_kernel<<<1, 256, 0, stream>>>(partial, BB / 16, out);
    }
}

// Round 6
// 34.904 us; speedup vs baseline: 1.4206x; 1.4206x over previous
//
#include <hip/hip_runtime.h>
#include <math.h>
#include <stdint.h>

// Problem constants (match reference)
#define BB 65536
#define KK 10
#define EE 128
#define VV 100000

constexpr int BLOCK = 256;
constexpr int BPB   = 32;            // 32 groups of 8 lanes per block
constexpr int GRID  = BB / BPB;      // 2048 blocks (fp8 path)

constexpr size_t TBL_OFF   = 32768;              // fp8 table offset in ws
constexpr size_t TBL_BYTES = (size_t)VV * EE;    // 12.8 MB fp8

__device__ __forceinline__ float softplus_f(float x) {
    float ax = fabsf(x);
    return fmaxf(x, 0.0f) + __logf(1.0f + __expf(-ax));
}

// ---- fp32 -> fp8 e4m3 (RNE, HW cvt) table conversion --------------------
__global__ __launch_bounds__(256) void
convert_fp8_kernel(const float* __restrict__ emb, uint4* __restrict__ tbl) {
    const int nq = VV * EE / 16;                 // 800K chunks of 16 elems
    const int stride = gridDim.x * blockDim.x;
    for (int q = blockIdx.x * blockDim.x + threadIdx.x; q < nq; q += stride) {
        const float4* src = (const float4*)emb + (size_t)q * 4;
        const float4 f0 = src[0], f1 = src[1], f2 = src[2], f3 = src[3];
        uint32_t w[4];
        int v;
        v = 0;
        v = __builtin_amdgcn_cvt_pk_fp8_f32(f0.x, f0.y, v, false);
        v = __builtin_amdgcn_cvt_pk_fp8_f32(f0.z, f0.w, v, true);
        w[0] = (uint32_t)v;
        v = 0;
        v = __builtin_amdgcn_cvt_pk_fp8_f32(f1.x, f1.y, v, false);
        v = __builtin_amdgcn_cvt_pk_fp8_f32(f1.z, f1.w, v, true);
        w[1] = (uint32_t)v;
        v = 0;
        v = __builtin_amdgcn_cvt_pk_fp8_f32(f2.x, f2.y, v, false);
        v = __builtin_amdgcn_cvt_pk_fp8_f32(f2.z, f2.w, v, true);
        w[2] = (uint32_t)v;
        v = 0;
        v = __builtin_amdgcn_cvt_pk_fp8_f32(f3.x, f3.y, v, false);
        v = __builtin_amdgcn_cvt_pk_fp8_f32(f3.z, f3.w, v, true);
        w[3] = (uint32_t)v;
        tbl[q] = make_uint4(w[0], w[1], w[2], w[3]);
    }
}

// ---- fp8 gather + loss ---------------------------------------------------
__device__ __forceinline__ void decode16(const uint4& u, float* f) {
    const uint32_t a[4] = {u.x, u.y, u.z, u.w};
    #pragma unroll
    for (int i = 0; i < 4; ++i) {
        auto lo = __builtin_amdgcn_cvt_pk_f32_fp8((int)a[i], false);
        auto hi = __builtin_amdgcn_cvt_pk_f32_fp8((int)a[i], true);
        f[4 * i + 0] = lo[0];
        f[4 * i + 1] = lo[1];
        f[4 * i + 2] = hi[0];
        f[4 * i + 3] = hi[1];
    }
}

__device__ __forceinline__ float dotd16(const float* cf, const uint4& u) {
    const uint32_t a[4] = {u.x, u.y, u.z, u.w};
    float s = 0.0f;
    #pragma unroll
    for (int i = 0; i < 4; ++i) {
        auto lo = __builtin_amdgcn_cvt_pk_f32_fp8((int)a[i], false);
        auto hi = __builtin_amdgcn_cvt_pk_f32_fp8((int)a[i], true);
        s = fmaf(cf[4 * i + 0], lo[0], s);
        s = fmaf(cf[4 * i + 1], lo[1], s);
        s = fmaf(cf[4 * i + 2], hi[0], s);
        s = fmaf(cf[4 * i + 3], hi[1], s);
    }
    return s;
}

__global__ __launch_bounds__(BLOCK, 4) void
w2v_loss_fp8_kernel(const int* __restrict__ cw,
                    const int* __restrict__ ow,
                    const int* __restrict__ neg,
                    const uint4* __restrict__ rows,   // one row = 8 uint4 (128 B)
                    float* __restrict__ partial) {
    const int tid = threadIdx.x;
    const int li  = tid & 7;               // lane-in-group (8-lane groups)
    const int grp = tid >> 3;              // 0..31
    const int b0  = blockIdx.x * BPB;

    // ---- stage this block's 384 indices through LDS (coalesced) ----
    __shared__ int s_cw[BPB];
    __shared__ int s_ow[BPB];
    __shared__ int s_neg[BPB * KK];
    if (tid < BPB)              s_cw[tid]       = cw[b0 + tid];
    else if (tid < 2 * BPB)     s_ow[tid - BPB] = ow[b0 + tid - BPB];
    for (int i = tid; i < BPB * KK; i += BLOCK) s_neg[i] = neg[b0 * KK + i];
    __syncthreads();

    // ---- issue ALL 12 row gathers before any compute (max MLP) ----
    const int c = s_cw[grp];
    const int o = s_ow[grp];
    const uint4 ec = rows[(size_t)c * 8 + li];
    const uint4 eo = rows[(size_t)o * 8 + li];
    uint4 en[KK];
    #pragma unroll
    for (int k = 0; k < KK; ++k)
        en[k] = rows[(size_t)s_neg[grp * KK + k] * 8 + li];

    // ---- compute ----
    float cf[16];
    decode16(ec, cf);
    float pd = dotd16(cf, eo);
    float nd[KK];
    #pragma unroll
    for (int k = 0; k < KK; ++k) nd[k] = dotd16(cf, en[k]);

    // Reduce across the 8-lane group: masks 1,2,4.
    #pragma unroll
    for (int s = 1; s < 8; s <<= 1) {
        pd += __shfl_xor(pd, s);
        #pragma unroll
        for (int k = 0; k < KK; ++k) nd[k] += __shfl_xor(nd[k], s);
    }

    float loss = softplus_f(-pd);
    #pragma unroll
    for (int k = 0; k < KK; ++k) loss += softplus_f(nd[k]);

    __shared__ float smem[BPB];
    if (li == 0) smem[grp] = loss;
    __syncthreads();
    if (tid == 0) {
        float s = 0.0f;
        #pragma unroll
        for (int g = 0; g < BPB; ++g) s += smem[g];
        partial[blockIdx.x] = s;     // per-block partial; no cross-XCD atomics
    }
}

// ---- fp32 fallback (ws too small; round-2 structure) --------------------
__device__ __forceinline__ float dot8(const float4& a0, const float4& a1,
                                      const float4& b0, const float4& b1) {
    float s = a0.x * b0.x;
    s = fmaf(a0.y, b0.y, s); s = fmaf(a0.z, b0.z, s); s = fmaf(a0.w, b0.w, s);
    s = fmaf(a1.x, b1.x, s); s = fmaf(a1.y, b1.y, s);
    s = fmaf(a1.z, b1.z, s); s = fmaf(a1.w, b1.w, s);
    return s;
}

__global__ __launch_bounds__(BLOCK) void
w2v_loss_f32_kernel(const int* __restrict__ cw,
                    const int* __restrict__ ow,
                    const int* __restrict__ neg,
                    const float* __restrict__ emb,
                    float* __restrict__ partial) {
    const int tid = threadIdx.x;
    const int li  = tid & 15;
    const int grp = tid >> 4;
    const int b   = blockIdx.x * 16 + grp;

    const int c = cw[b];
    const int o = ow[b];
    const float4* ebase = (const float4*)emb;
    const size_t f4 = (size_t)li * 2;

    const float4 ec0 = ebase[(size_t)c * 32 + f4];
    const float4 ec1 = ebase[(size_t)c * 32 + f4 + 1];
    const float4 eo0 = ebase[(size_t)o * 32 + f4];
    const float4 eo1 = ebase[(size_t)o * 32 + f4 + 1];

    float pd = dot8(ec0, ec1, eo0, eo1);
    float nd[KK];
    #pragma unroll
    for (int k = 0; k < KK; ++k) {
        const int n = neg[b * KK + k];
        const float4 en0 = ebase[(size_t)n * 32 + f4];
        const float4 en1 = ebase[(size_t)n * 32 + f4 + 1];
        nd[k] = dot8(ec0, ec1, en0, en1);
    }
    #pragma unroll
    for (int s = 1; s < 16; s <<= 1) {
        pd += __shfl_xor(pd, s);
        #pragma unroll
        for (int k = 0; k < KK; ++k) nd[k] += __shfl_xor(nd[k], s);
    }
    float loss = softplus_f(-pd);
    #pragma unroll
    for (int k = 0; k < KK; ++k) loss += softplus_f(nd[k]);

    __shared__ float smem[16];
    if (li == 0) smem[grp] = loss;
    __syncthreads();
    if (tid == 0) {
        float s = 0.0f;
        #pragma unroll
        for (int g = 0; g < 16; ++g) s += smem[g];
        partial[blockIdx.x] = s;
    }
}

__global__ __launch_bounds__(256) void
w2v_reduce_kernel(const float* __restrict__ partial, int n, float* __restrict__ out) {
    __shared__ float smem[256];
    float s = 0.0f;
    for (int i = threadIdx.x; i < n; i += 256) s += partial[i];
    smem[threadIdx.x] = s;
    __syncthreads();
    for (int step = 128; step > 0; step >>= 1) {
        if (threadIdx.x < step) smem[threadIdx.x] += smem[threadIdx.x + step];
        __syncthreads();
    }
    if (threadIdx.x == 0) out[0] = smem[0] / (float)BB;
}

extern "C" void kernel_launch(void* const* d_in, const int* in_sizes, int n_in,
                              void* d_out, int out_size, void* d_ws, size_t ws_size,
                              hipStream_t stream) {
    const int*   cw  = (const int*)d_in[0];
    const int*   ow  = (const int*)d_in[1];
    const int*   neg = (const int*)d_in[2];
    const float* emb = (const float*)d_in[3];
    float* out     = (float*)d_out;
    float* partial = (float*)d_ws;

    if (ws_size >= TBL_OFF + TBL_BYTES) {
        uint4* tbl = (uint4*)((char*)d_ws + TBL_OFF);
        convert_fp8_kernel<<<2048, 256, 0, stream>>>(emb, tbl);
        w2v_loss_fp8_kernel<<<GRID, BLOCK, 0, stream>>>(cw, ow, neg, tbl, partial);
        w2v_reduce_kernel<<<1, 256, 0, stream>>>(partial, GRID, out);
    } else {
        w2v_loss_f32_kernel<<<BB / 16, BLOCK, 0, stream>>>(cw, ow, neg, emb, partial);
        w2v_reduce_kernel<<<1, 256, 0, stream>>>(partial, BB / 16, out);
    }
}